// Round 8
// baseline (107.769 us; speedup 1.0000x reference)
//
#include <hip/hip_runtime.h>
#include <hip/hip_fp16.h>

// HDP-HMM forward-backward, exact-semantics parallel decomposition. R8:
//  - Ln=16 -> 16384 chunks/dir, 2048 scan blocks = 8192 waves = 100% occupancy
//    (R7 grid was half-sized: 4096 waves, 30% occupancy, 75% stall)
//  - u stored fp16 packed per-chunk into out's own float slot (first 640B of
//    each 1280B chunk slot; same block reads halves then writes floats, fenced
//    by __syncthreads) -> scale3 traffic 84->63MB, no extra ws
//  - combine PG=16

namespace {
constexpr int Tn = 262144;
constexpr int Kn = 20;
constexpr int Fn = 16;
constexpr float EPSF = 1e-10f;
constexpr float TINY = 1e-35f;

constexpr int Ln3 = 16;
constexpr int Wn3 = 20;
constexpr int NC3 = Tn / Ln3;          // 16384 chunks per direction
constexpr int NBF = NC3 / 16;          // 1024 scan blocks per direction
constexpr int NBS3 = NC3 / 4;          // 4096 scale blocks per direction
constexpr int SPC = Ln3 * Kn;          // floats per chunk slot in out = 320

// ws layout (floats); ~23.5 MB
constexpr size_t OFF_P    = 0;
constexpr size_t OFF_W    = 400;
constexpr size_t OFF_CK   = 420;
constexpr size_t OFF_MVIV = 440;
constexpr size_t OFF_E    = 1152;
constexpr size_t OFF_MF   = OFF_E + (size_t)Tn*20 + 64;
constexpr size_t OFF_MB   = OFF_MF + (size_t)Tn;
constexpr size_t OFF_MATF = OFF_MB + (size_t)Tn;
constexpr size_t OFF_MATB = OFF_MATF + 4*(size_t)NC3;
constexpr size_t OFF_SF   = OFF_MATB + 4*(size_t)NC3;
constexpr size_t OFF_SB   = OFF_SF + NC3;
constexpr size_t OFF_END  = OFF_SB + NC3;
}

#if __has_builtin(__builtin_amdgcn_rcpf)
#define FRCP(x) __builtin_amdgcn_rcpf(x)
#else
#define FRCP(x) (1.0f/(x))
#endif

template<int CTRL>
__device__ __forceinline__ float dpp_add(float v) {
  int s = __builtin_amdgcn_update_dpp(0, __float_as_int(v), CTRL, 0xF, 0xF, true);
  return v + __int_as_float(s);
}

// Sum across each 16-lane row, broadcast. Pure DPP.
__device__ __forceinline__ float reduce16(float v) {
  v = dpp_add<0xB1>(v);
  v = dpp_add<0x4E>(v);
  v = dpp_add<0x141>(v);
  v = dpp_add<0x140>(v);
  return v;
}

// ============================ prep ============================
__global__ __launch_bounds__(64) void prep_kernel(
    const float* beta_logits, const float* pi_logits,
    const float* means, const float* log_vars, float* ws)
{
  int k = threadIdx.x;
  if (k < Kn) {
    float row[Kn];
    float mx = -1e30f;
#pragma unroll
    for (int j = 0; j < Kn; ++j) { row[j] = pi_logits[k*Kn + j]; mx = fmaxf(mx, row[j]); }
    float s = 0.f;
#pragma unroll
    for (int j = 0; j < Kn; ++j) { row[j] = expf(row[j] - mx); s += row[j]; }
    float invs = 1.0f / s;
#pragma unroll
    for (int j = 0; j < Kn; ++j) ws[OFF_P + k*Kn + j] = row[j] * invs;
    float ck = 0.f;
#pragma unroll
    for (int f = 0; f < Fn; ++f) {
      float lv  = log_vars[k*Fn + f];
      float var = expf(lv) + 1e-6f;
      float iv  = 1.0f / var;
      float mu  = means[k*Fn + f];
      ((float2*)(ws + OFF_MVIV))[k*Fn + f] = make_float2(mu * iv, iv);
      ck += mu*mu*iv + logf(6.2831853071795864f * var);
    }
    ws[OFF_CK + k] = ck;
  } else if (k == Kn) {
    float cp = 1.f;
#pragma unroll
    for (int i = 0; i < Kn; ++i) {
      float b = 1.0f / (1.0f + expf(-beta_logits[i]));
      ws[OFF_W + i] = b * cp;
      cp *= (1.0f - b);
    }
  }
}

// ============================ emission ============================
__global__ __launch_bounds__(320) void emis_kernel(const float* __restrict__ obs, float* ws)
{
  __shared__ __align__(16) float so[64][20];
  __shared__ __align__(16) float scm[16][24];
  __shared__ __align__(16) float scv[16][24];
  __shared__ __align__(16) float sck[20];
  const int tid = threadIdx.x;
  const int t0 = blockIdx.x * 64;

  if (tid < 256) {
    float4 v = ((const float4*)(obs + (size_t)t0 * Fn))[tid];
    int r = tid >> 2, j = tid & 3;
    *(float4*)&so[r][j*4] = v;
  } else {
    int i = tid - 256;
#pragma unroll
    for (int q = 0; q < 5; ++q) {
      int idx = i * 5 + q;
      float2 c2 = ((const float2*)(ws + OFF_MVIV))[idx];
      int k = idx >> 4, f = idx & 15;
      scm[f][k] = c2.x;
      scv[f][k] = c2.y;
    }
    if (i < Kn) sck[i] = ws[OFF_CK + i];
  }
  __syncthreads();

  const int tl = tid / 5;
  const int k0 = (tid - tl*5) * 4;

  float o[16];
  *(float4*)&o[0]  = *(const float4*)&so[tl][0];
  *(float4*)&o[4]  = *(const float4*)&so[tl][4];
  *(float4*)&o[8]  = *(const float4*)&so[tl][8];
  *(float4*)&o[12] = *(const float4*)&so[tl][12];

  float s1x=0.f,s1y=0.f,s1z=0.f,s1w=0.f;
  float s2x=0.f,s2y=0.f,s2z=0.f,s2w=0.f;
#pragma unroll
  for (int f = 0; f < Fn; ++f) {
    float4 cm = *(const float4*)&scm[f][k0];
    float4 cv = *(const float4*)&scv[f][k0];
    float ov = o[f];
    s1x = fmaf(cv.x * ov, ov, s1x); s2x = fmaf(cm.x, ov, s2x);
    s1y = fmaf(cv.y * ov, ov, s1y); s2y = fmaf(cm.y, ov, s2y);
    s1z = fmaf(cv.z * ov, ov, s1z); s2z = fmaf(cm.z, ov, s2z);
    s1w = fmaf(cv.w * ov, ov, s1w); s2w = fmaf(cm.w, ov, s2w);
  }
  float4 ckv = *(const float4*)&sck[k0];
  float4 rr;
  rr.x = __expf(fmaf(-0.5f, s1x + ckv.x, s2x));
  rr.y = __expf(fmaf(-0.5f, s1y + ckv.y, s2y));
  rr.z = __expf(fmaf(-0.5f, s1z + ckv.z, s2z));
  rr.w = __expf(fmaf(-0.5f, s1w + ckv.w, s2w));
  *(float4*)(ws + OFF_E + (size_t)(t0 + tl)*20 + k0) = rr;
}

// ============================ scan ============================
// 16-lane groups; u stored fp16 into the owning chunk's slot of `out`.
__global__ __launch_bounds__(256) void scan3_kernel(float* ws, float* out)
{
  __shared__ __align__(16) float xsh[16][20];
  const int tid = threadIdx.x;
  const int g   = tid >> 4;
  const int ll  = tid & 15;
  const bool hi = (ll < 4);
  const int l4  = 16 + (ll & 3);
  const bool isF = ((int)blockIdx.x < NBF);
  const int c = (isF ? (int)blockIdx.x : (int)blockIdx.x - NBF) * 16 + g;
  const float* E = ws + OFF_E;
  float* xg = &xsh[g][0];

  float Pv0[Kn], Pv1[Kn];
#pragma unroll
  for (int k = 0; k < Kn; ++k) {
    if (isF) {
      Pv0[k] = ws[OFF_P + k*Kn + ll];
      float p1 = ws[OFF_P + k*Kn + l4];
      Pv1[k] = hi ? p1 : 0.f;
    } else {
      Pv0[k] = ws[OFF_P + ll*Kn + k];
      float p1 = ws[OFF_P + l4*Kn + k];
      Pv1[k] = hi ? p1 : 0.f;
    }
  }

  float Ma = 1.f, Mc = 0.f, Md = 1.f;
  float* mArr = ws + (isF ? OFF_MF : OFF_MB);
  __half* uH = (__half*)(out + (isF ? (size_t)0 : (size_t)Tn * Kn) + (size_t)c * SPC);

  auto mobius = [&](float m) {
    float na = m * Ma;
    float nc = fmaf(EPSF, Mc, na);
    float nd = EPSF * Md;
    float mx = fmaxf(nc, nd);
    float lam = (mx > 0.f) ? FRCP(mx) : 1.0f;
    Ma = na*lam; Mc = nc*lam; Md = nd*lam;
  };
  auto matvec2 = [&](float& r0, float& r1) {
    float xv[20];
    *(float4*)&xv[0]  = *(const float4*)&xg[0];
    *(float4*)&xv[4]  = *(const float4*)&xg[4];
    *(float4*)&xv[8]  = *(const float4*)&xg[8];
    *(float4*)&xv[12] = *(const float4*)&xg[12];
    *(float4*)&xv[16] = *(const float4*)&xg[16];
    float A0 = xv[0]*Pv0[0], A1 = xv[1]*Pv0[1];
    float B0 = xv[0]*Pv1[0], B1 = xv[1]*Pv1[1];
#pragma unroll
    for (int k = 2; k < 20; k += 2) {
      A0 = fmaf(xv[k],   Pv0[k],   A0);
      A1 = fmaf(xv[k+1], Pv0[k+1], A1);
      B0 = fmaf(xv[k],   Pv1[k],   B0);
      B1 = fmaf(xv[k+1], Pv1[k+1], B1);
    }
    r0 = A0 + A1; r1 = B0 + B1;
  };

  if (isF) {
    const int bodyStart = c * Ln3;
    const int tend = bodyStart + Ln3 - 1;
    const int t0 = (c == 0) ? 0 : (bodyStart - Wn3);
    float e0a = E[t0*20 + ll],     e1a = E[t0*20 + l4];
    float v0, v1;
    if (c == 0) {
      v0 = ws[OFF_W + ll] * e0a;
      v1 = hi ? ws[OFF_W + l4] * e1a : 0.f;
    } else {
      v0 = 0.05f * e0a;
      v1 = hi ? 0.05f * e1a : 0.f;
    }
    float sv = reduce16(v0 + v1);
    float m = sv;
    float iV = (sv > TINY) ? FRCP(sv) : 1.0f;
    if (sv <= TINY) { v0 = 0.05f; v1 = hi ? 0.05f : 0.f; }
    if (c == 0) {
      if (ll == 0) mArr[0] = m;
      mobius(m);
      uH[ll] = __float2half(v0 * iV);
      if (hi) uH[l4] = __float2half(v1 * iV);
    }
    float A = m * iV;
    float rho = (m > TINY) ? FRCP(m) : 1.0f;
    float e0b = E[(t0+1)*20 + ll], e1b = E[(t0+1)*20 + l4];
    float e0c = E[(t0+2)*20 + ll], e1c = E[(t0+2)*20 + l4];

#define FWD_STEP(REC)                                                     \
    {                                                                     \
      xg[ll] = v0;                                                        \
      if (hi) xg[16 + ll] = v1;                                           \
      float acc0, acc1; matvec2(acc0, acc1);                              \
      float er0 = e0a * rho, er1 = e1a * rho;                             \
      e0a = e0b; e0b = e0c; e0c = E[(t+3)*20 + ll];                       \
      e1a = e1b; e1b = e1c; e1c = E[(t+3)*20 + l4];                       \
      v0 = acc0 * er0; v1 = acc1 * er1;                                   \
      float sv2 = reduce16(v0 + v1);                                      \
      float mn = sv2 * A;                                                 \
      float iVn = (sv2 > TINY) ? FRCP(sv2) : 1.0f;                        \
      if (sv2 <= TINY) { v0 = 0.05f; v1 = hi ? 0.05f : 0.f; }             \
      if (REC) {                                                          \
        if (ll == 0) mArr[t] = mn;                                        \
        mobius(mn);                                                       \
        int lt = t - bodyStart;                                           \
        uH[lt*Kn + ll] = __float2half(v0 * iVn);                          \
        if (hi) uH[lt*Kn + 16 + ll] = __float2half(v1 * iVn);             \
      }                                                                   \
      A = mn * iVn;                                                       \
      rho = (mn > TINY) ? FRCP(mn) : 1.0f;                                \
    }

    for (int t = t0 + 1; t < bodyStart; ++t) FWD_STEP(false)
    const int bstart2 = (c == 0) ? 1 : bodyStart;
    for (int t = bstart2; t <= tend; ++t) FWD_STEP(true)
#undef FWD_STEP
    if (ll == 0) ((float4*)(ws + OFF_MATF))[c] = make_float4(Ma, Mc, Md, 0.f);
  } else {
    const int bodyStart = c * Ln3;
    const int top = bodyStart + Ln3 - 1;
    int r0 = top + Wn3; if (r0 > Tn - 1) r0 = Tn - 1;
    float v0 = 0.05f, v1 = hi ? 0.05f : 0.f;
    float sv = reduce16(v0 + v1);
    float iV = (sv > TINY) ? FRCP(sv) : 1.0f;
    float A = iV;
    float rho = 1.0f;
    float e0a = E[r0*20 + ll],     e1a = E[r0*20 + l4];
    float e0b = E[(r0-1)*20 + ll], e1b = E[(r0-1)*20 + l4];
    float e0c = E[(r0-2)*20 + ll], e1c = E[(r0-2)*20 + l4];

#define BWD_STEP(REC)                                                     \
    {                                                                     \
      xg[ll] = v0 * e0a;                                                  \
      if (hi) xg[16 + ll] = v1 * e1a;                                     \
      float acc0, acc1; matvec2(acc0, acc1);                              \
      v0 = acc0 * rho; v1 = acc1 * rho;                                   \
      e0a = e0b; e0b = e0c; e0c = E[(r-2)*20 + ll];                       \
      e1a = e1b; e1b = e1c; e1c = E[(r-2)*20 + l4];                       \
      float sv2 = reduce16(v0 + v1);                                      \
      float mn = sv2 * A;                                                 \
      float iVn = (sv2 > TINY) ? FRCP(sv2) : 1.0f;                        \
      if (sv2 <= TINY) { v0 = 0.05f; v1 = hi ? 0.05f : 0.f; }             \
      if (REC) {                                                          \
        if (ll == 0) mArr[r+1] = mn;                                      \
        mobius(mn);                                                       \
        int lr = r - bodyStart;                                           \
        uH[lr*Kn + ll] = __float2half(v0 * iVn);                          \
        if (hi) uH[lr*Kn + 16 + ll] = __float2half(v1 * iVn);             \
      }                                                                   \
      A = mn * iVn;                                                       \
      rho = (mn > TINY) ? FRCP(mn) : 1.0f;                                \
    }

    for (int r = r0 - 1; r > top; --r) BWD_STEP(false)
    int rb = (r0 - 1 < top) ? (r0 - 1) : top;
    for (int r = rb; r >= bodyStart; --r) BWD_STEP(true)
#undef BWD_STEP
    if (ll == 0) ((float4*)(ws + OFF_MATB))[NC3 - 1 - c] = make_float4(Ma, Mc, Md, 0.f);
  }
}

// ============================ combine ============================
__global__ __launch_bounds__(1024) void combine4_kernel(float* ws, float* out)
{
  __shared__ float wag[16][3];
  __shared__ float wpre[16][3];
  const bool isF = (blockIdx.x == 0);
  const float4* M4 = (const float4*)(ws + (isF ? OFF_MATF : OFF_MATB));
  float* sArr = ws + (isF ? OFF_SF : OFF_SB);
  const float s0 = isF ? 1.0f : 20.0f;
  constexpr int PG = NC3 / 1024;   // 16
  const int tid  = threadIdx.x;
  const int lane = tid & 63;
  const int wid  = tid >> 6;

  float4 mm[PG];
#pragma unroll
  for (int i = 0; i < PG; ++i) mm[i] = M4[tid*PG + i];

  float a = 1.f, cc = 0.f, d = 1.f;
#pragma unroll
  for (int i = 0; i < PG; ++i) {
    float na = mm[i].x * a;
    float nc = fmaf(mm[i].y, a, mm[i].z * cc);
    float nd = mm[i].z * d;
    float mx = fmaxf(na, fmaxf(nc, nd));
    float lam = (mx > 0.f) ? FRCP(mx) : 1.0f;
    a = na*lam; cc = nc*lam; d = nd*lam;
  }

  float ia = a, ic = cc, id = d;
  for (int off = 1; off < 64; off <<= 1) {
    float pa = __shfl_up(ia, off, 64);
    float pc = __shfl_up(ic, off, 64);
    float pd = __shfl_up(id, off, 64);
    if (lane >= off) {
      float na = ia * pa;
      float nc = fmaf(ic, pa, id * pc);
      float nd = id * pd;
      float mx = fmaxf(na, fmaxf(nc, nd));
      float lam = (mx > 0.f) ? FRCP(mx) : 1.0f;
      ia = na*lam; ic = nc*lam; id = nd*lam;
    }
  }
  if (lane == 63) { wag[wid][0] = ia; wag[wid][1] = ic; wag[wid][2] = id; }
  __syncthreads();

  if (tid == 0) {
    float ea = 1.f, ec = 0.f, ed = 1.f;
#pragma unroll
    for (int w = 0; w < 16; ++w) {
      wpre[w][0] = ea; wpre[w][1] = ec; wpre[w][2] = ed;
      float na = wag[w][0] * ea;
      float nc = fmaf(wag[w][1], ea, wag[w][2] * ec);
      float nd = wag[w][2] * ed;
      float mx = fmaxf(na, fmaxf(nc, nd));
      float lam = (mx > 0.f) ? FRCP(mx) : 1.0f;
      ea = na*lam; ec = nc*lam; ed = nd*lam;
    }
    if (isF) {
      float den = fmaf(ec, s0, ed);
      float sfin = (den > 0.f) ? (ea * s0)/den : 0.f;
      out[(size_t)2 * Tn * Kn] = logf(sfin + EPSF);
    }
  }
  __syncthreads();

  float ea = __shfl_up(ia, 1, 64);
  float ec = __shfl_up(ic, 1, 64);
  float ed = __shfl_up(id, 1, 64);
  if (lane == 0) { ea = 1.f; ec = 0.f; ed = 1.f; }
  float pa = wpre[wid][0], pc = wpre[wid][1], pd = wpre[wid][2];
  float xa = ea * pa;
  float xc = fmaf(ec, pa, ed * pc);
  float xd = ed * pd;

  float num = xa * s0, den = fmaf(xc, s0, xd);
  float s = (den > 0.f) ? num/den : 0.f;
#pragma unroll
  for (int i = 0; i < PG; ++i) {
    sArr[tid*PG + i] = s;
    float nn = mm[i].x * s, dd = fmaf(mm[i].y, s, mm[i].z);
    s = (dd > 0.f) ? nn/dd : 0.f;
  }
}

// ============================ scale ============================
// Phase 1: per chunk, serial sigma chain into LDS.
// Phase 2: read this chunk's fp16 u (first 640B of its own slot), convert,
// scale, write f32 in place. __syncthreads fences read-before-write.
__global__ __launch_bounds__(128) void scale3_kernel(float* ws, float* out)
{
  __shared__ float sig[4][Ln3];
  const int tid = threadIdx.x;
  const int g   = tid >> 5;
  const int jj  = tid & 31;
  const bool isF = ((int)blockIdx.x < NBS3);
  const int c = (isF ? (int)blockIdx.x : (int)blockIdx.x - NBS3) * 4 + g;
  float* base = out + (isF ? (size_t)0 : (size_t)Tn * Kn) + (size_t)c * SPC;
  const __half* hp = (const __half*)base;

  if (isF) {
    const float* mArr = ws + OFF_MF;
    float s = ws[OFF_SF + c];
    const int t0 = c * Ln3;
#pragma unroll
    for (int i = 0; i < Ln3; ++i) {
      float mm = mArr[t0 + i];
      float z = s * mm;
      float sn = z * FRCP(z + EPSF);
      if (jj == 0) sig[g][i] = sn;
      s = sn;
    }
  } else {
    const float* mArr = ws + OFF_MB;
    const int slot = NC3 - 1 - c;
    float s = ws[OFF_SB + slot];
    const int bodyStart = c * Ln3;
    const int top = bodyStart + Ln3 - 1;
#pragma unroll
    for (int r = top; r >= bodyStart; --r) {
      if (r == Tn - 1) {
        if (jj == 0) sig[g][Ln3 - 1] = 1.0f;
        continue;
      }
      float mm = mArr[r + 1];
      float z = s * mm;
      float sn = z * FRCP(z + EPSF);
      if (jj == 0) sig[g][r - bodyStart] = sn;
      s = sn;
    }
  }

  // phase 2: lane jj covers elements [jj*10, jj*10+10) -> single t = jj>>1
  float vals[10];
#pragma unroll
  for (int q = 0; q < 10; ++q) vals[q] = __half2float(hp[jj*10 + q]);
  __syncthreads();   // all reads (and sig writes) complete before any write

  const int tl = jj >> 1;
  float sg = sig[g][tl];
  const bool onesRow = (!isF && c == NC3 - 1 && tl == Ln3 - 1);
#pragma unroll
  for (int q = 0; q < 10; ++q) {
    float vv = onesRow ? 1.0f : vals[q] * sg;
    base[jj*10 + q] = vv;
  }
}

extern "C" void kernel_launch(void* const* d_in, const int* in_sizes, int n_in,
                              void* d_out, int out_size, void* d_ws, size_t ws_size,
                              hipStream_t stream) {
  const float* obs         = (const float*)d_in[0];
  const float* beta_logits = (const float*)d_in[1];
  const float* pi_logits   = (const float*)d_in[2];
  const float* means       = (const float*)d_in[3];
  const float* log_vars    = (const float*)d_in[4];
  float* out = (float*)d_out;
  float* ws  = (float*)d_ws;

  hipLaunchKernelGGL(prep_kernel, dim3(1), dim3(64), 0, stream,
                     beta_logits, pi_logits, means, log_vars, ws);
  hipLaunchKernelGGL(emis_kernel, dim3(Tn/64), dim3(320), 0, stream, obs, ws);
  hipLaunchKernelGGL(scan3_kernel, dim3(2*NBF), dim3(256), 0, stream, ws, out);
  hipLaunchKernelGGL(combine4_kernel, dim3(2), dim3(1024), 0, stream, ws, out);
  hipLaunchKernelGGL(scale3_kernel, dim3(2*NBS3), dim3(128), 0, stream, ws, out);
}

// Round 9
// 94.544 us; speedup vs baseline: 1.1399x; 1.1399x over previous
//
#include <hip/hip_runtime.h>
#include <hip/hip_fp16.h>

// HDP-HMM forward-backward, exact-semantics parallel decomposition. R9:
//  - scan re-packed to 8-lane groups (states j, 8+j, 16+(j&3); last 4 duplicated
//    on lanes 4-7): ~2x fewer wave-inst per chunk-step, 3-DPP reduce, zero
//    exec-mask branches (dup same-address writes are winner-identical)
//  - Ln=16/Wn=16, 4096 waves (16 waves/CU cap at ~110 VGPR)
//  - u staged as packed half2 u32; scale kernel: lane=t, 3x uint4 read,
//    5x float4 coalesced write, sigma chain in-register

namespace {
constexpr int Tn = 262144;
constexpr int Kn = 20;
constexpr int Fn = 16;
constexpr float EPSF = 1e-10f;
constexpr float TINY = 1e-35f;

constexpr int Ln3 = 16;
constexpr int Wn3 = 16;
constexpr int NC3 = Tn / Ln3;          // 16384 chunks per direction
constexpr int NBF4 = NC3 / 32;         // 512 scan blocks per direction (32 chunks/block)
constexpr int NBSC = NC3 / 8;          // 2048 scale blocks per direction (8 chunks/block)
constexpr int SPC = Ln3 * Kn;          // floats per chunk slot in out = 320

// ws layout (floats); ~23.5 MB
constexpr size_t OFF_P    = 0;
constexpr size_t OFF_W    = 400;
constexpr size_t OFF_CK   = 420;
constexpr size_t OFF_MVIV = 440;
constexpr size_t OFF_E    = 1152;
constexpr size_t OFF_MF   = OFF_E + (size_t)Tn*20 + 64;
constexpr size_t OFF_MB   = OFF_MF + (size_t)Tn;
constexpr size_t OFF_MATF = OFF_MB + (size_t)Tn;
constexpr size_t OFF_MATB = OFF_MATF + 4*(size_t)NC3;
constexpr size_t OFF_SF   = OFF_MATB + 4*(size_t)NC3;
constexpr size_t OFF_SB   = OFF_SF + NC3;
constexpr size_t OFF_END  = OFF_SB + NC3;
}

#if __has_builtin(__builtin_amdgcn_rcpf)
#define FRCP(x) __builtin_amdgcn_rcpf(x)
#else
#define FRCP(x) (1.0f/(x))
#endif

template<int CTRL>
__device__ __forceinline__ float dpp_add(float v) {
  int s = __builtin_amdgcn_update_dpp(0, __float_as_int(v), CTRL, 0xF, 0xF, true);
  return v + __int_as_float(s);
}

// Sum across each 8-lane group, broadcast. xor1, xor2, then half-mirror
// (= xor4 once quads are uniform). All group-contained within 8 lanes.
__device__ __forceinline__ float reduce8(float v) {
  v = dpp_add<0xB1>(v);
  v = dpp_add<0x4E>(v);
  v = dpp_add<0x141>(v);
  return v;
}

__device__ __forceinline__ unsigned packh2(float a, float b) {
  __half2 h2 = __floats2half2_rn(a, b);
  return *(unsigned*)&h2;
}

// ============================ prep ============================
__global__ __launch_bounds__(64) void prep_kernel(
    const float* beta_logits, const float* pi_logits,
    const float* means, const float* log_vars, float* ws)
{
  int k = threadIdx.x;
  if (k < Kn) {
    float row[Kn];
    float mx = -1e30f;
#pragma unroll
    for (int j = 0; j < Kn; ++j) { row[j] = pi_logits[k*Kn + j]; mx = fmaxf(mx, row[j]); }
    float s = 0.f;
#pragma unroll
    for (int j = 0; j < Kn; ++j) { row[j] = expf(row[j] - mx); s += row[j]; }
    float invs = 1.0f / s;
#pragma unroll
    for (int j = 0; j < Kn; ++j) ws[OFF_P + k*Kn + j] = row[j] * invs;
    float ck = 0.f;
#pragma unroll
    for (int f = 0; f < Fn; ++f) {
      float lv  = log_vars[k*Fn + f];
      float var = expf(lv) + 1e-6f;
      float iv  = 1.0f / var;
      float mu  = means[k*Fn + f];
      ((float2*)(ws + OFF_MVIV))[k*Fn + f] = make_float2(mu * iv, iv);
      ck += mu*mu*iv + logf(6.2831853071795864f * var);
    }
    ws[OFF_CK + k] = ck;
  } else if (k == Kn) {
    float cp = 1.f;
#pragma unroll
    for (int i = 0; i < Kn; ++i) {
      float b = 1.0f / (1.0f + expf(-beta_logits[i]));
      ws[OFF_W + i] = b * cp;
      cp *= (1.0f - b);
    }
  }
}

// ============================ emission ============================
__global__ __launch_bounds__(320) void emis_kernel(const float* __restrict__ obs, float* ws)
{
  __shared__ __align__(16) float so[64][20];
  __shared__ __align__(16) float scm[16][24];
  __shared__ __align__(16) float scv[16][24];
  __shared__ __align__(16) float sck[20];
  const int tid = threadIdx.x;
  const int t0 = blockIdx.x * 64;

  if (tid < 256) {
    float4 v = ((const float4*)(obs + (size_t)t0 * Fn))[tid];
    int r = tid >> 2, j = tid & 3;
    *(float4*)&so[r][j*4] = v;
  } else {
    int i = tid - 256;
#pragma unroll
    for (int q = 0; q < 5; ++q) {
      int idx = i * 5 + q;
      float2 c2 = ((const float2*)(ws + OFF_MVIV))[idx];
      int k = idx >> 4, f = idx & 15;
      scm[f][k] = c2.x;
      scv[f][k] = c2.y;
    }
    if (i < Kn) sck[i] = ws[OFF_CK + i];
  }
  __syncthreads();

  const int tl = tid / 5;
  const int k0 = (tid - tl*5) * 4;

  float o[16];
  *(float4*)&o[0]  = *(const float4*)&so[tl][0];
  *(float4*)&o[4]  = *(const float4*)&so[tl][4];
  *(float4*)&o[8]  = *(const float4*)&so[tl][8];
  *(float4*)&o[12] = *(const float4*)&so[tl][12];

  float s1x=0.f,s1y=0.f,s1z=0.f,s1w=0.f;
  float s2x=0.f,s2y=0.f,s2z=0.f,s2w=0.f;
#pragma unroll
  for (int f = 0; f < Fn; ++f) {
    float4 cm = *(const float4*)&scm[f][k0];
    float4 cv = *(const float4*)&scv[f][k0];
    float ov = o[f];
    s1x = fmaf(cv.x * ov, ov, s1x); s2x = fmaf(cm.x, ov, s2x);
    s1y = fmaf(cv.y * ov, ov, s1y); s2y = fmaf(cm.y, ov, s2y);
    s1z = fmaf(cv.z * ov, ov, s1z); s2z = fmaf(cm.z, ov, s2z);
    s1w = fmaf(cv.w * ov, ov, s1w); s2w = fmaf(cm.w, ov, s2w);
  }
  float4 ckv = *(const float4*)&sck[k0];
  float4 rr;
  rr.x = __expf(fmaf(-0.5f, s1x + ckv.x, s2x));
  rr.y = __expf(fmaf(-0.5f, s1y + ckv.y, s2y));
  rr.z = __expf(fmaf(-0.5f, s1z + ckv.z, s2z));
  rr.w = __expf(fmaf(-0.5f, s1w + ckv.w, s2w));
  *(float4*)(ws + OFF_E + (size_t)(t0 + tl)*20 + k0) = rr;
}

// ============================ scan (8-lane groups) ============================
// Lane j of a group owns states j, 8+j, 16+(j&3) (last 4 duplicated on lanes 4-7).
// Block = 256 thr = 32 groups; blocks [0,NBF4) fwd, [NBF4,2*NBF4) bwd.
__global__ __launch_bounds__(256, 4) void scan4_kernel(float* ws, float* out)
{
  __shared__ __align__(16) float xsh[32][20];
  const int tid = threadIdx.x;
  const int g   = tid >> 3;        // 0..31
  const int j   = tid & 7;
  const int q   = j & 3;
  const int s1i = 8 + j;
  const int s2i = 16 + q;
  const bool isF = ((int)blockIdx.x < NBF4);
  const int c = (isF ? (int)blockIdx.x : (int)blockIdx.x - NBF4) * 32 + g;
  const float* E = ws + OFF_E;
  float* xg = &xsh[g][0];

  float Pv0[Kn], Pv1[Kn], Pv2[Kn];
#pragma unroll
  for (int k = 0; k < Kn; ++k) {
    if (isF) {
      Pv0[k] = ws[OFF_P + k*Kn + j];
      Pv1[k] = ws[OFF_P + k*Kn + s1i];
      Pv2[k] = ws[OFF_P + k*Kn + s2i];
    } else {
      Pv0[k] = ws[OFF_P + j*Kn + k];
      Pv1[k] = ws[OFF_P + s1i*Kn + k];
      Pv2[k] = ws[OFF_P + s2i*Kn + k];
    }
  }

  float Ma = 1.f, Mc = 0.f, Md = 1.f;
  float* mArr = ws + (isF ? OFF_MF : OFF_MB);
  unsigned* uS = (unsigned*)(out + (isF ? (size_t)0 : (size_t)Tn * Kn) + (size_t)c * SPC);

  auto mobius = [&](float m) {
    float na = m * Ma;
    float nc = fmaf(EPSF, Mc, na);
    float nd = EPSF * Md;
    float mx = fmaxf(nc, nd);
    float lam = (mx > 0.f) ? FRCP(mx) : 1.0f;
    Ma = na*lam; Mc = nc*lam; Md = nd*lam;
  };
  auto matvec3 = [&](float& r0, float& r1, float& r2) {
    float xv[20];
    *(float4*)&xv[0]  = *(const float4*)&xg[0];
    *(float4*)&xv[4]  = *(const float4*)&xg[4];
    *(float4*)&xv[8]  = *(const float4*)&xg[8];
    *(float4*)&xv[12] = *(const float4*)&xg[12];
    *(float4*)&xv[16] = *(const float4*)&xg[16];
    float a0 = xv[0]*Pv0[0], a1 = xv[1]*Pv0[1];
    float b0 = xv[0]*Pv1[0], b1 = xv[1]*Pv1[1];
    float c0 = xv[0]*Pv2[0], c1 = xv[1]*Pv2[1];
#pragma unroll
    for (int k = 2; k < 20; k += 2) {
      a0 = fmaf(xv[k],   Pv0[k],   a0);
      a1 = fmaf(xv[k+1], Pv0[k+1], a1);
      b0 = fmaf(xv[k],   Pv1[k],   b0);
      b1 = fmaf(xv[k+1], Pv1[k+1], b1);
      c0 = fmaf(xv[k],   Pv2[k],   c0);
      c1 = fmaf(xv[k+1], Pv2[k+1], c1);
    }
    r0 = a0 + a1; r1 = b0 + b1; r2 = c0 + c1;
  };

  if (isF) {
    const int bodyStart = c * Ln3;
    const int tend = bodyStart + Ln3 - 1;
    const int t0 = (c == 0) ? 0 : (bodyStart - Wn3);
    float e0a = E[t0*20 + j], e1a = E[t0*20 + s1i], e2a = E[t0*20 + s2i];
    float v0, v1, v2;
    if (c == 0) {
      v0 = ws[OFF_W + j]   * e0a;
      v1 = ws[OFF_W + s1i] * e1a;
      v2 = ws[OFF_W + s2i] * e2a;
    } else {
      v0 = 0.05f * e0a; v1 = 0.05f * e1a; v2 = 0.05f * e2a;
    }
    float sv = reduce8(fmaf(0.5f, v2, v0 + v1));
    float m = sv;
    float iV = (sv > TINY) ? FRCP(sv) : 1.0f;
    if (sv <= TINY) { v0 = 0.05f; v1 = 0.05f; v2 = 0.05f; }
    if (c == 0) {
      mArr[0] = m;           // all 8 lanes, same addr, same value
      mobius(m);
      uS[j] = packh2(v0 * iV, v1 * iV);
      uS[8 + q] = packh2(v2 * iV, 0.f);
    }
    float A = m * iV;
    float rho = (m > TINY) ? FRCP(m) : 1.0f;
    float e0b = E[(t0+1)*20 + j], e1b = E[(t0+1)*20 + s1i], e2b = E[(t0+1)*20 + s2i];
    float e0c = E[(t0+2)*20 + j], e1c = E[(t0+2)*20 + s1i], e2c = E[(t0+2)*20 + s2i];

#define FWD_STEP(REC)                                                     \
    {                                                                     \
      xg[j] = v0; xg[s1i] = v1; xg[s2i] = v2;                             \
      float acc0, acc1, acc2; matvec3(acc0, acc1, acc2);                  \
      float er0 = e0a * rho, er1 = e1a * rho, er2 = e2a * rho;            \
      e0a = e0b; e0b = e0c; e0c = E[(t+3)*20 + j];                        \
      e1a = e1b; e1b = e1c; e1c = E[(t+3)*20 + s1i];                      \
      e2a = e2b; e2b = e2c; e2c = E[(t+3)*20 + s2i];                      \
      v0 = acc0 * er0; v1 = acc1 * er1; v2 = acc2 * er2;                  \
      float sv2 = reduce8(fmaf(0.5f, v2, v0 + v1));                      \
      float mn = sv2 * A;                                                 \
      float iVn = (sv2 > TINY) ? FRCP(sv2) : 1.0f;                        \
      if (sv2 <= TINY) { v0 = 0.05f; v1 = 0.05f; v2 = 0.05f; }            \
      if (REC) {                                                          \
        mArr[t] = mn;                                                     \
        mobius(mn);                                                       \
        int lt = t - bodyStart;                                           \
        uS[lt*12 + j] = packh2(v0 * iVn, v1 * iVn);                       \
        uS[lt*12 + 8 + q] = packh2(v2 * iVn, 0.f);                        \
      }                                                                   \
      A = mn * iVn;                                                       \
      rho = (mn > TINY) ? FRCP(mn) : 1.0f;                                \
    }

    for (int t = t0 + 1; t < bodyStart; ++t) FWD_STEP(false)
    const int bstart2 = (c == 0) ? 1 : bodyStart;
    for (int t = bstart2; t <= tend; ++t) FWD_STEP(true)
#undef FWD_STEP
    ((float4*)(ws + OFF_MATF))[c] = make_float4(Ma, Mc, Md, 0.f);
  } else {
    const int bodyStart = c * Ln3;
    const int top = bodyStart + Ln3 - 1;
    int r0 = top + Wn3; if (r0 > Tn - 1) r0 = Tn - 1;   // r0==Tn-1 => exact init
    float v0 = 0.05f, v1 = 0.05f, v2 = 0.05f;
    float sv = reduce8(fmaf(0.5f, v2, v0 + v1));         // ~1.0
    float iV = (sv > TINY) ? FRCP(sv) : 1.0f;
    float A = iV;
    float rho = 1.0f;
    float e0a = E[r0*20 + j], e1a = E[r0*20 + s1i], e2a = E[r0*20 + s2i];
    float e0b = E[(r0-1)*20 + j], e1b = E[(r0-1)*20 + s1i], e2b = E[(r0-1)*20 + s2i];
    float e0c = E[(r0-2)*20 + j], e1c = E[(r0-2)*20 + s1i], e2c = E[(r0-2)*20 + s2i];

#define BWD_STEP(REC)                                                     \
    {                                                                     \
      xg[j] = v0 * e0a; xg[s1i] = v1 * e1a; xg[s2i] = v2 * e2a;           \
      float acc0, acc1, acc2; matvec3(acc0, acc1, acc2);                  \
      v0 = acc0 * rho; v1 = acc1 * rho; v2 = acc2 * rho;                  \
      e0a = e0b; e0b = e0c; e0c = E[(r-2)*20 + j];                        \
      e1a = e1b; e1b = e1c; e1c = E[(r-2)*20 + s1i];                      \
      e2a = e2b; e2b = e2c; e2c = E[(r-2)*20 + s2i];                      \
      float sv2 = reduce8(fmaf(0.5f, v2, v0 + v1));                      \
      float mn = sv2 * A;                                                 \
      float iVn = (sv2 > TINY) ? FRCP(sv2) : 1.0f;                        \
      if (sv2 <= TINY) { v0 = 0.05f; v1 = 0.05f; v2 = 0.05f; }            \
      if (REC) {                                                          \
        mArr[r+1] = mn;                                                   \
        mobius(mn);                                                       \
        int lr = r - bodyStart;                                           \
        uS[lr*12 + j] = packh2(v0 * iVn, v1 * iVn);                       \
        uS[lr*12 + 8 + q] = packh2(v2 * iVn, 0.f);                        \
      }                                                                   \
      A = mn * iVn;                                                       \
      rho = (mn > TINY) ? FRCP(mn) : 1.0f;                                \
    }

    for (int r = r0 - 1; r > top; --r) BWD_STEP(false)
    int rb = (r0 - 1 < top) ? (r0 - 1) : top;
    for (int r = rb; r >= bodyStart; --r) BWD_STEP(true)
#undef BWD_STEP
    ((float4*)(ws + OFF_MATB))[NC3 - 1 - c] = make_float4(Ma, Mc, Md, 0.f);
  }
}

// ============================ combine ============================
__global__ __launch_bounds__(1024) void combine4_kernel(float* ws, float* out)
{
  __shared__ float wag[16][3];
  __shared__ float wpre[16][3];
  const bool isF = (blockIdx.x == 0);
  const float4* M4 = (const float4*)(ws + (isF ? OFF_MATF : OFF_MATB));
  float* sArr = ws + (isF ? OFF_SF : OFF_SB);
  const float s0 = isF ? 1.0f : 20.0f;
  constexpr int PG = NC3 / 1024;   // 16
  const int tid  = threadIdx.x;
  const int lane = tid & 63;
  const int wid  = tid >> 6;

  float4 mm[PG];
#pragma unroll
  for (int i = 0; i < PG; ++i) mm[i] = M4[tid*PG + i];

  float a = 1.f, cc = 0.f, d = 1.f;
#pragma unroll
  for (int i = 0; i < PG; ++i) {
    float na = mm[i].x * a;
    float nc = fmaf(mm[i].y, a, mm[i].z * cc);
    float nd = mm[i].z * d;
    float mx = fmaxf(na, fmaxf(nc, nd));
    float lam = (mx > 0.f) ? FRCP(mx) : 1.0f;
    a = na*lam; cc = nc*lam; d = nd*lam;
  }

  float ia = a, ic = cc, id = d;
  for (int off = 1; off < 64; off <<= 1) {
    float pa = __shfl_up(ia, off, 64);
    float pc = __shfl_up(ic, off, 64);
    float pd = __shfl_up(id, off, 64);
    if (lane >= off) {
      float na = ia * pa;
      float nc = fmaf(ic, pa, id * pc);
      float nd = id * pd;
      float mx = fmaxf(na, fmaxf(nc, nd));
      float lam = (mx > 0.f) ? FRCP(mx) : 1.0f;
      ia = na*lam; ic = nc*lam; id = nd*lam;
    }
  }
  if (lane == 63) { wag[wid][0] = ia; wag[wid][1] = ic; wag[wid][2] = id; }
  __syncthreads();

  if (tid == 0) {
    float ea = 1.f, ec = 0.f, ed = 1.f;
#pragma unroll
    for (int w = 0; w < 16; ++w) {
      wpre[w][0] = ea; wpre[w][1] = ec; wpre[w][2] = ed;
      float na = wag[w][0] * ea;
      float nc = fmaf(wag[w][1], ea, wag[w][2] * ec);
      float nd = wag[w][2] * ed;
      float mx = fmaxf(na, fmaxf(nc, nd));
      float lam = (mx > 0.f) ? FRCP(mx) : 1.0f;
      ea = na*lam; ec = nc*lam; ed = nd*lam;
    }
    if (isF) {
      float den = fmaf(ec, s0, ed);
      float sfin = (den > 0.f) ? (ea * s0)/den : 0.f;
      out[(size_t)2 * Tn * Kn] = logf(sfin + EPSF);
    }
  }
  __syncthreads();

  float ea = __shfl_up(ia, 1, 64);
  float ec = __shfl_up(ic, 1, 64);
  float ed = __shfl_up(id, 1, 64);
  if (lane == 0) { ea = 1.f; ec = 0.f; ed = 1.f; }
  float pa = wpre[wid][0], pc = wpre[wid][1], pd = wpre[wid][2];
  float xa = ea * pa;
  float xc = fmaf(ec, pa, ed * pc);
  float xd = ed * pd;

  float num = xa * s0, den = fmaf(xc, s0, xd);
  float s = (den > 0.f) ? num/den : 0.f;
#pragma unroll
  for (int i = 0; i < PG; ++i) {
    sArr[tid*PG + i] = s;
    float nn = mm[i].x * s, dd = fmaf(mm[i].y, s, mm[i].z);
    s = (dd > 0.f) ? nn/dd : 0.f;
  }
}

// ============================ scale ============================
// 128 thr = 8 groups x 16 lanes; lane ll handles one t of its chunk.
// Sigma chain in-register (predicated capture); 3x uint4 read, 5x float4 write.
__global__ __launch_bounds__(128) void scale4_kernel(float* ws, float* out)
{
  const int tid = threadIdx.x;
  const int g   = tid >> 4;
  const int ll  = tid & 15;
  const bool isF = ((int)blockIdx.x < NBSC);
  const int c = (isF ? (int)blockIdx.x : (int)blockIdx.x - NBSC) * 8 + g;
  float* base = out + (isF ? (size_t)0 : (size_t)Tn * Kn) + (size_t)c * SPC;
  const unsigned* uS = (const unsigned*)base;

  float mySig = 1.0f;
  if (isF) {
    const float* mA = ws + OFF_MF;
    float s = ws[OFF_SF + c];
    const int t0 = c * Ln3;
#pragma unroll
    for (int i = 0; i < Ln3; ++i) {
      float z = s * mA[t0 + i];
      float sn = z * FRCP(z + EPSF);
      if (i == ll) mySig = sn;
      s = sn;
    }
  } else {
    const float* mA = ws + OFF_MB;
    float s = ws[OFF_SB + (NC3 - 1 - c)];
    const int top = c * Ln3 + Ln3 - 1;
#pragma unroll
    for (int i = 0; i < Ln3; ++i) {
      int r = top - i;
      float sn;
      if (r == Tn - 1) sn = s;
      else {
        float z = s * mA[r + 1];
        sn = z * FRCP(z + EPSF);
      }
      if (i == Ln3 - 1 - ll) mySig = sn;
      s = sn;
    }
  }

  uint4 ua = ((const uint4*)(uS + ll*12))[0];
  uint4 ub = ((const uint4*)(uS + ll*12))[1];
  uint4 uc = ((const uint4*)(uS + ll*12))[2];
  __syncthreads();   // compiler/memory fence: staged reads before f32 overwrites

  const bool onesRow = (!isF && c == NC3 - 1 && ll == Ln3 - 1);
  float sg = mySig;
  unsigned slots[12] = {ua.x,ua.y,ua.z,ua.w, ub.x,ub.y,ub.z,ub.w, uc.x,uc.y,uc.z,uc.w};
  float o[20];
#pragma unroll
  for (int jj = 0; jj < 8; ++jj) {
    __half2 h2 = *(__half2*)&slots[jj];
    float2 f2 = __half22float2(h2);
    o[jj]     = f2.x * sg;
    o[8 + jj] = f2.y * sg;
  }
#pragma unroll
  for (int qq = 0; qq < 4; ++qq) {
    __half2 h2 = *(__half2*)&slots[8 + qq];
    float2 f2 = __half22float2(h2);
    o[16 + qq] = f2.x * sg;
  }
  if (onesRow) {
#pragma unroll
    for (int k = 0; k < 20; ++k) o[k] = 1.0f;
  }
  float* dst = base + ll * 20;
  *(float4*)&dst[0]  = *(float4*)&o[0];
  *(float4*)&dst[4]  = *(float4*)&o[4];
  *(float4*)&dst[8]  = *(float4*)&o[8];
  *(float4*)&dst[12] = *(float4*)&o[12];
  *(float4*)&dst[16] = *(float4*)&o[16];
}

extern "C" void kernel_launch(void* const* d_in, const int* in_sizes, int n_in,
                              void* d_out, int out_size, void* d_ws, size_t ws_size,
                              hipStream_t stream) {
  const float* obs         = (const float*)d_in[0];
  const float* beta_logits = (const float*)d_in[1];
  const float* pi_logits   = (const float*)d_in[2];
  const float* means       = (const float*)d_in[3];
  const float* log_vars    = (const float*)d_in[4];
  float* out = (float*)d_out;
  float* ws  = (float*)d_ws;

  hipLaunchKernelGGL(prep_kernel, dim3(1), dim3(64), 0, stream,
                     beta_logits, pi_logits, means, log_vars, ws);
  hipLaunchKernelGGL(emis_kernel, dim3(Tn/64), dim3(320), 0, stream, obs, ws);
  hipLaunchKernelGGL(scan4_kernel, dim3(2*NBF4), dim3(256), 0, stream, ws, out);
  hipLaunchKernelGGL(combine4_kernel, dim3(2), dim3(1024), 0, stream, ws, out);
  hipLaunchKernelGGL(scale4_kernel, dim3(2*NBSC), dim3(128), 0, stream, ws, out);
}